// Round 11
// baseline (64.441 us; speedup 1.0000x reference)
//
#include <hip/hip_runtime.h>
#include <math.h>

#define N_ROWS 262144
#define D 128
#define C 64
#define NB1 2048          // ce_hist blocks; 128 rows each
#define RPB1 128
#define SCB 256           // scatter blocks; 1024 rows each (8 hist segments)
#define CSTRIDE 4608      // padded per-class index slot (count ~4096 + 8 sigma)
#define PB 1024           // proto blocks = 64 classes x 16 octants
#define PT 512
#define TMAX 9            // ceil(CSTRIDE / (512 groups per class))
#define OCTW 132          // per-block partial: 128 sums + cnt + sq + pad

// ws layout (4-byte units)
#define OFF_HIST   0                          // int[NB1*C]
#define OFF_BASES  (NB1 * C)                  // int[NB1*C]
#define OFF_IDX    (2 * NB1 * C)              // int[C*CSTRIDE]
#define OFF_CNT    (2 * NB1 * C + C * CSTRIDE) // int[C]
#define OFF_CEB    (OFF_CNT + C)              // float[NB1]
#define OFF_OCT    (OFF_CEB + NB1)            // float[PB*OCTW]

// asm-issued 32B gather: compiler cannot sink/serialize these
__device__ __forceinline__ void gload8(float4& a, float4& b, const float* p) {
  asm volatile("global_load_dwordx4 %0, %2, off\n\t"
               "global_load_dwordx4 %1, %2, off offset:16"
               : "=&v"(a), "=&v"(b)
               : "v"(p));
}

// ---------------- K1: cross-entropy + per-block label histogram -------------
__global__ __launch_bounds__(256, 8) void ce_hist_kernel(
    const float* __restrict__ logits, const int* __restrict__ labels,
    float* __restrict__ ceB, int* __restrict__ hist) {
  __shared__ float sCe[4];
  __shared__ int sH[C];
  const int tid = threadIdx.x;
  if (tid < C) sH[tid] = 0;
  __syncthreads();

  const int wave = tid >> 6, lane = tid & 63;
  const int g = lane >> 4, lp = lane & 15;
  const int rowBase = blockIdx.x * RPB1 + wave * 32 + g;
  float ce_acc = 0.f;

  // 4-deep named-register prefetch pipeline
  float4 tA, tB, tC, tD;
  int lA, lB, lC, lD;
  {
    const float* lg = logits + (size_t)rowBase * C + lp * 4;
    tA = *(const float4*)(lg + 0 * 4 * C);  lA = labels[rowBase + 0];
    tB = *(const float4*)(lg + 1 * 4 * C);  lB = labels[rowBase + 4];
    tC = *(const float4*)(lg + 2 * 4 * C);  lC = labels[rowBase + 8];
    tD = *(const float4*)(lg + 3 * 4 * C);  lD = labels[rowBase + 12];
  }

#pragma unroll
  for (int it = 0; it < 8; ++it) {
    const int r4 = it & 3;                   // compile-time under full unroll
    const float4 t4 = r4 == 0 ? tA : r4 == 1 ? tB : r4 == 2 ? tC : tD;
    const int lab = r4 == 0 ? lA : r4 == 1 ? lB : r4 == 2 ? lC : lD;
    if (it + 4 < 8) {                        // refill freed stage
      const int row = rowBase + (it + 4) * 4;
      const float4 nt = *(const float4*)(logits + (size_t)row * C + lp * 4);
      const int nl = labels[row];
      if (r4 == 0)      { tA = nt; lA = nl; }
      else if (r4 == 1) { tB = nt; lB = nl; }
      else if (r4 == 2) { tC = nt; lC = nl; }
      else              { tD = nt; lD = nl; }
    }
    float p = __expf(t4.x) + __expf(t4.y) + __expf(t4.z) + __expf(t4.w);
    float tl = 0.f;
    if ((lab >> 2) == lp) {
      const int k = lab & 3;
      tl = k == 0 ? t4.x : k == 1 ? t4.y : k == 2 ? t4.z : t4.w;
    }
    p += __shfl_xor(p, 1);  tl += __shfl_xor(tl, 1);
    p += __shfl_xor(p, 2);  tl += __shfl_xor(tl, 2);
    p += __shfl_xor(p, 4);  tl += __shfl_xor(tl, 4);
    p += __shfl_xor(p, 8);  tl += __shfl_xor(tl, 8);
    if (lp == 0) {
      ce_acc += __logf(p) - tl;
      atomicAdd(&sH[lab], 1);
    }
  }
  ce_acc += __shfl_xor(ce_acc, 16);
  ce_acc += __shfl_xor(ce_acc, 32);
  if (lane == 0) sCe[wave] = ce_acc;
  __syncthreads();
  if (tid == 0) ceB[blockIdx.x] = sCe[0] + sCe[1] + sCe[2] + sCe[3];
  if (tid < C) hist[blockIdx.x * C + tid] = sH[tid];
}

// ---------------- K2: per-class exclusive scan over 2048 segment hists ------
__global__ __launch_bounds__(256) void scan_kernel(
    const int* __restrict__ hist, int* __restrict__ bases,
    int* __restrict__ cnts) {
  __shared__ int sA[256], sB[256];
  const int c = blockIdx.x, t = threadIdx.x;
  int h[8], tot = 0;
#pragma unroll
  for (int j = 0; j < 8; ++j) {
    h[j] = hist[(t * 8 + j) * C + c];
    tot += h[j];
  }
  sA[t] = tot;
  __syncthreads();
#pragma unroll
  for (int st = 0; st < 8; ++st) {   // Hillis-Steele inclusive, alt buffers
    const int off = 1 << st;
    if (st & 1) sA[t] = sB[t] + ((t >= off) ? sB[t - off] : 0);
    else        sB[t] = sA[t] + ((t >= off) ? sA[t - off] : 0);
    __syncthreads();
  }
  const int incl = sA[t];            // st=7 (odd) wrote sA
  int run = incl - tot;              // exclusive prefix for this thread's chunk
#pragma unroll
  for (int j = 0; j < 8; ++j) {
    bases[(t * 8 + j) * C + c] = run;
    run += h[j];
  }
  if (t == 255) cnts[c] = incl;
}

// ---------------- K3: scatter row indices into padded class slots -----------
// 1024 rows per block (8 segments); cursor seeded at segment-8b base. Block's
// writes fill exactly [bases[8b], bases[8b+8]) per class, any order inside.
__global__ __launch_bounds__(512) void scatter_kernel(
    const int* __restrict__ labels, const int* __restrict__ bases,
    int* __restrict__ idx) {
  __shared__ int sCur[C];
  const int t = threadIdx.x, b = blockIdx.x;
  if (t < C) sCur[t] = bases[(b * 8) * C + t];
  __syncthreads();
  const int row = b * 1024 + t * 2;
  const int2 l = *(const int2*)(labels + row);
  const int p0 = atomicAdd(&sCur[l.x], 1);
  idx[l.x * CSTRIDE + p0] = row;
  const int p1 = atomicAdd(&sCur[l.y], 1);
  idx[l.y * CSTRIDE + p1] = row + 1;
}

// ---------------- K4: class-uniform gather, asm counted-vmcnt pipeline ------
__global__ __launch_bounds__(PT, 4) void proto_kernel(
    const float* __restrict__ emb, const int* __restrict__ idxArr,
    const int* __restrict__ cnts, float* __restrict__ oct) {
  __shared__ float sR[8][OCTW];
  const int tid = threadIdx.x;
  const int wave = tid >> 6, lane = tid & 63;
  const int g = lane >> 4, lp = lane & 15;
  const int b = blockIdx.x;
  const int c = b >> 4, o = b & 15;
  const int gg = o * 32 + wave * 4 + g;      // group slot in class: 0..511
  const int n = cnts[c];
  const int nm1 = (n > 0) ? n - 1 : 0;
  const int* ip = idxArr + c * CSTRIDE;

  int rI[TMAX];
#pragma unroll
  for (int t = 0; t < TMAX; ++t) {
    const int e = gg + 512 * t;
    rI[t] = ip[e < nm1 ? e : nm1];
  }
  // force index loads complete BEFORE the pipeline, so the compiler never
  // inserts a draining vmcnt(0) between our asm loads
#pragma unroll
  for (int t = 0; t < TMAX; ++t) asm volatile("" :: "v"(rI[t]));
  __builtin_amdgcn_sched_barrier(0);

  float4 s0a, s0b, s1a, s1b, s2a, s2b, s3a, s3b, s4a, s4b, s5a, s5b;
  gload8(s0a, s0b, emb + (size_t)rI[0] * D + lp * 8);
  gload8(s1a, s1b, emb + (size_t)rI[1] * D + lp * 8);
  gload8(s2a, s2b, emb + (size_t)rI[2] * D + lp * 8);
  gload8(s3a, s3b, emb + (size_t)rI[3] * D + lp * 8);
  gload8(s4a, s4b, emb + (size_t)rI[4] * D + lp * 8);
  gload8(s5a, s5b, emb + (size_t)rI[5] * D + lp * 8);

  float4 accA = {0.f, 0.f, 0.f, 0.f}, accB = {0.f, 0.f, 0.f, 0.f};
  float cnt = 0.f, sq = 0.f;

  auto consume = [&](const float4 ea, const float4 eb, const int t) {
    float ss = ea.x * ea.x + ea.y * ea.y + ea.z * ea.z + ea.w * ea.w +
               eb.x * eb.x + eb.y * eb.y + eb.z * eb.z + eb.w * eb.w;
    ss += __shfl_xor(ss, 1);
    ss += __shfl_xor(ss, 2);
    ss += __shfl_xor(ss, 4);
    ss += __shfl_xor(ss, 8);
    const float inv = 1.0f / fmaxf(sqrtf(ss), 1e-12f);
    const bool valid = (gg + 512 * t) < n;
    const float sc = valid ? inv : 0.f;      // validity folded into the scale
    accA.x += ea.x * sc;  accA.y += ea.y * sc;
    accA.z += ea.z * sc;  accA.w += ea.w * sc;
    accB.x += eb.x * sc;  accB.y += eb.y * sc;
    accB.z += eb.z * sc;  accB.w += eb.w * sc;
    if (lp == 0) {
      cnt += valid ? 1.f : 0.f;
      sq += valid ? ss * inv * inv : 0.f;
    }
  };

// counted vmcnt: steady state keeps 10-12 loads in flight; drains 8,6,4,2,0
#define PSTEP(T, NW, SA, SB)                          \
  asm volatile("s_waitcnt vmcnt(" #NW ")");           \
  __builtin_amdgcn_sched_barrier(0);                  \
  consume(SA, SB, T);

  PSTEP(0, 10, s0a, s0b)  gload8(s0a, s0b, emb + (size_t)rI[6] * D + lp * 8);
  PSTEP(1, 10, s1a, s1b)  gload8(s1a, s1b, emb + (size_t)rI[7] * D + lp * 8);
  PSTEP(2, 10, s2a, s2b)  gload8(s2a, s2b, emb + (size_t)rI[8] * D + lp * 8);
  PSTEP(3, 10, s3a, s3b)
  PSTEP(4, 8,  s4a, s4b)
  PSTEP(5, 6,  s5a, s5b)
  PSTEP(6, 4,  s0a, s0b)
  PSTEP(7, 2,  s1a, s1b)
  PSTEP(8, 0,  s2a, s2b)
#undef PSTEP

  // cross-group reduce (groups share the lp->dim map)
#pragma unroll
  for (int off = 16; off <= 32; off <<= 1) {
    accA.x += __shfl_xor(accA.x, off);  accA.y += __shfl_xor(accA.y, off);
    accA.z += __shfl_xor(accA.z, off);  accA.w += __shfl_xor(accA.w, off);
    accB.x += __shfl_xor(accB.x, off);  accB.y += __shfl_xor(accB.y, off);
    accB.z += __shfl_xor(accB.z, off);  accB.w += __shfl_xor(accB.w, off);
    cnt += __shfl_xor(cnt, off);
    sq += __shfl_xor(sq, off);
  }

  if (lane < 16) {
    *(float4*)&sR[wave][lp * 8] = accA;
    *(float4*)&sR[wave][lp * 8 + 4] = accB;
  }
  if (lane == 0) { sR[wave][128] = cnt; sR[wave][129] = sq; }
  __syncthreads();
  if (tid < 130) {
    float s = 0.f;
#pragma unroll
    for (int w = 0; w < 8; ++w) s += sR[w][tid];
    oct[(size_t)b * OCTW + tid] = s;
  }
}

// ---------------- K5: class stats + CE sum + final scalar (one block) -------
__global__ __launch_bounds__(1024) void classfinal_kernel(
    const float* __restrict__ oct, const float* __restrict__ ceB,
    float* __restrict__ out) {
  __shared__ float sPer[C], sVal[C], sCe[16];
  const int tid = threadIdx.x, wave = tid >> 6, lane = tid & 63;

  // CE: 2048 block partials over 1024 threads
  float ce = ceB[tid] + ceB[tid + 1024];
#pragma unroll
  for (int off = 1; off < 64; off <<= 1) ce += __shfl_xor(ce, off);
  if (lane == 0) sCe[wave] = ce;

  // wave w handles classes 4w..4w+3; lane owns dims lane and 64+lane
#pragma unroll
  for (int q = 0; q < 4; ++q) {
    const int c = wave * 4 + q;
    float s0 = 0.f, s1 = 0.f, n = 0.f, sq = 0.f;
#pragma unroll
    for (int o = 0; o < 16; ++o) {
      const float* f = oct + (size_t)(c * 16 + o) * OCTW;
      s0 += f[lane];
      s1 += f[64 + lane];
      n += f[128];
      sq += f[129];
    }
    const float safe = fmaxf(n, 1.f);
    const float mu0 = s0 / safe, mu1 = s1 / safe;
    float msq = mu0 * mu0 + mu1 * mu1;
#pragma unroll
    for (int off = 1; off < 64; off <<= 1) msq += __shfl_xor(msq, off);
    if (lane == 0) {
      const float ssd = sq - n * msq;
      const bool valid = n > 1.f;
      sPer[c] = valid ? ssd / safe : 0.f;
      sVal[c] = valid ? 1.f : 0.f;
    }
  }
  __syncthreads();
  if (tid == 0) {
    float pr = 0.f, nv = 0.f, c2 = 0.f;
#pragma unroll
    for (int c = 0; c < C; ++c) { pr += sPer[c]; nv += sVal[c]; }
#pragma unroll
    for (int w = 0; w < 16; ++w) c2 += sCe[w];
    out[0] = 0.5f * (c2 / (float)N_ROWS) + 0.5f * (pr / fmaxf(nv, 1.f));
  }
}

extern "C" void kernel_launch(void* const* d_in, const int* in_sizes, int n_in,
                              void* d_out, int out_size, void* d_ws, size_t ws_size,
                              hipStream_t stream) {
  const float* emb = (const float*)d_in[0];
  const float* logits = (const float*)d_in[1];
  const int* labels = (const int*)d_in[2];
  int* wsi = (int*)d_ws;
  float* wsf = (float*)d_ws;
  float* out = (float*)d_out;

  int* hist = wsi + OFF_HIST;
  int* bases = wsi + OFF_BASES;
  int* idx = wsi + OFF_IDX;
  int* cnts = wsi + OFF_CNT;
  float* ceB = wsf + OFF_CEB;
  float* oct = wsf + OFF_OCT;

  ce_hist_kernel<<<NB1, 256, 0, stream>>>(logits, labels, ceB, hist);
  scan_kernel<<<C, 256, 0, stream>>>(hist, bases, cnts);
  scatter_kernel<<<SCB, 512, 0, stream>>>(labels, bases, idx);
  proto_kernel<<<PB, PT, 0, stream>>>(emb, idx, cnts, oct);
  classfinal_kernel<<<1, 1024, 0, stream>>>(oct, ceB, out);
}

// Round 12
// 52.967 us; speedup vs baseline: 1.2166x; 1.2166x over previous
//
#include <hip/hip_runtime.h>
#include <math.h>

#define N_ROWS 262144
#define D 128
#define C 64
#define CSTRIDE 4608      // padded per-class index slot (count ~4096 + 8 sigma)
#define BB 64             // build blocks; 4096 rows each
#define FB 1024           // fused blocks = 64 classes x 16 octants; 256 CE rows each
#define FT 512
#define TMAX 9            // ceil(CSTRIDE / (512 groups per class))
#define OCTW 132          // per-block partial: 128 sums + cnt + sq + pad

// ws layout (4-byte units)
#define OFF_IDX    0                          // int[C*CSTRIDE]
#define OFF_CNT    (C * CSTRIDE)              // int[C]
#define OFF_CEB    (OFF_CNT + C)              // float[FB]
#define OFF_OCT    (OFF_CEB + FB)             // float[FB*OCTW]
#define OFF_RES    (OFF_OCT + FB * OCTW)      // float[2*C]

// asm-issued 32B gather: compiler cannot sink/serialize these
__device__ __forceinline__ void gload8(float4& a, float4& b, const float* p) {
  asm volatile("global_load_dwordx4 %0, %2, off\n\t"
               "global_load_dwordx4 %1, %2, off offset:16"
               : "=&v"(a), "=&v"(b)
               : "v"(p));
}

// ---------------- K1: one-shot index build (hist+scan+scatter fused) --------
// Block b histograms its 4096 rows in LDS (keeping each row's within-block
// position from the atomicAdd return), claims a per-class base with one
// global atomicAdd per class, then writes indices. Within-class order is
// arbitrary — only the set matters. cnts ends exactly n per class.
__global__ __launch_bounds__(1024) void build_kernel(
    const int* __restrict__ labels, int* __restrict__ idx,
    int* __restrict__ cnts) {
  __shared__ int sH[C];
  __shared__ int sBase[C];
  const int t = threadIdx.x, b = blockIdx.x;
  if (t < C) sH[t] = 0;
  __syncthreads();
  const int row = b * 4096 + t * 4;
  const int4 l = *(const int4*)(labels + row);
  const int p0 = atomicAdd(&sH[l.x], 1);
  const int p1 = atomicAdd(&sH[l.y], 1);
  const int p2 = atomicAdd(&sH[l.z], 1);
  const int p3 = atomicAdd(&sH[l.w], 1);
  __syncthreads();
  if (t < C) sBase[t] = atomicAdd(&cnts[t], sH[t]);
  __syncthreads();
  idx[l.x * CSTRIDE + sBase[l.x] + p0] = row;
  idx[l.y * CSTRIDE + sBase[l.y] + p1] = row + 1;
  idx[l.z * CSTRIDE + sBase[l.z] + p2] = row + 2;
  idx[l.w * CSTRIDE + sBase[l.w] + p3] = row + 3;
}

// ---------------- K2: fused CE + class-gather, parity-staggered -------------
__global__ __launch_bounds__(FT, 4) void fused_kernel(
    const float* __restrict__ emb, const float* __restrict__ logits,
    const int* __restrict__ labels, const int* __restrict__ idxArr,
    const int* __restrict__ cnts, float* __restrict__ ceB,
    float* __restrict__ oct) {
  __shared__ float sCe[8];
  __shared__ float sR[8][OCTW];

  const int tid = threadIdx.x;
  const int wave = tid >> 6, lane = tid & 63;
  const int g = lane >> 4, lp = lane & 15;
  const int b = blockIdx.x;

  // ---- CE phase: 256 sequential rows, proven streaming skeleton ----
  auto ce_phase = [&]() {
    const int rowBase = b * 256 + wave * 32 + g;
    float ce_acc = 0.f;
    float4 tA, tB;
    int labA = 0, labB = 0;
    tA = *(const float4*)(logits + (size_t)rowBase * C + lp * 4);
    labA = labels[rowBase];
    tB = tA;
#pragma unroll
    for (int it = 0; it < 8; ++it) {
      const float4 t4 = (it & 1) ? tB : tA;
      const int lab = (it & 1) ? labB : labA;
      if (it + 1 < 8) {
        const int row = rowBase + (it + 1) * 4;
        if (it & 1) {
          tA = *(const float4*)(logits + (size_t)row * C + lp * 4);
          labA = labels[row];
        } else {
          tB = *(const float4*)(logits + (size_t)row * C + lp * 4);
          labB = labels[row];
        }
      }
      float p = __expf(t4.x) + __expf(t4.y) + __expf(t4.z) + __expf(t4.w);
      float tl = 0.f;
      if ((lab >> 2) == lp) {
        const int k = lab & 3;
        tl = k == 0 ? t4.x : k == 1 ? t4.y : k == 2 ? t4.z : t4.w;
      }
      p += __shfl_xor(p, 1);  tl += __shfl_xor(tl, 1);
      p += __shfl_xor(p, 2);  tl += __shfl_xor(tl, 2);
      p += __shfl_xor(p, 4);  tl += __shfl_xor(tl, 4);
      p += __shfl_xor(p, 8);  tl += __shfl_xor(tl, 8);
      if (lp == 0) ce_acc += __logf(p) - tl;
    }
    ce_acc += __shfl_xor(ce_acc, 16);
    ce_acc += __shfl_xor(ce_acc, 32);
    if (lane == 0) sCe[wave] = ce_acc;
    __syncthreads();
    if (tid == 0) {
      float s = 0.f;
#pragma unroll
      for (int w = 0; w < 8; ++w) s += sCe[w];
      ceB[b] = s;
    }
  };

  // ---- proto phase: asm-forced depth-6 gather pipeline ----
  auto proto_phase = [&]() {
    const int c = b >> 4, o = b & 15;
    const int gg = o * 32 + wave * 4 + g;    // group slot in class: 0..511
    const int n = cnts[c];
    const int nm1 = (n > 0) ? n - 1 : 0;
    const int* ip = idxArr + c * CSTRIDE;

    int rI[TMAX];
#pragma unroll
    for (int t = 0; t < TMAX; ++t) {
      const int e = gg + 512 * t;
      rI[t] = ip[e < nm1 ? e : nm1];
    }
    // force index loads complete BEFORE the pipeline, so the compiler never
    // inserts a draining vmcnt(0) between our asm loads
#pragma unroll
    for (int t = 0; t < TMAX; ++t) asm volatile("" :: "v"(rI[t]));
    __builtin_amdgcn_sched_barrier(0);

    float4 s0a, s0b, s1a, s1b, s2a, s2b, s3a, s3b, s4a, s4b, s5a, s5b;
    gload8(s0a, s0b, emb + (size_t)rI[0] * D + lp * 8);
    gload8(s1a, s1b, emb + (size_t)rI[1] * D + lp * 8);
    gload8(s2a, s2b, emb + (size_t)rI[2] * D + lp * 8);
    gload8(s3a, s3b, emb + (size_t)rI[3] * D + lp * 8);
    gload8(s4a, s4b, emb + (size_t)rI[4] * D + lp * 8);
    gload8(s5a, s5b, emb + (size_t)rI[5] * D + lp * 8);

    float4 accA = {0.f, 0.f, 0.f, 0.f}, accB = {0.f, 0.f, 0.f, 0.f};
    float cnt = 0.f, sq = 0.f;

    auto consume = [&](const float4 ea, const float4 eb, const int t) {
      float ss = ea.x * ea.x + ea.y * ea.y + ea.z * ea.z + ea.w * ea.w +
                 eb.x * eb.x + eb.y * eb.y + eb.z * eb.z + eb.w * eb.w;
      ss += __shfl_xor(ss, 1);
      ss += __shfl_xor(ss, 2);
      ss += __shfl_xor(ss, 4);
      ss += __shfl_xor(ss, 8);
      const float inv = 1.0f / fmaxf(sqrtf(ss), 1e-12f);
      const bool valid = (gg + 512 * t) < n;
      const float sc = valid ? inv : 0.f;    // validity folded into the scale
      accA.x += ea.x * sc;  accA.y += ea.y * sc;
      accA.z += ea.z * sc;  accA.w += ea.w * sc;
      accB.x += eb.x * sc;  accB.y += eb.y * sc;
      accB.z += eb.z * sc;  accB.w += eb.w * sc;
      if (lp == 0) {
        cnt += valid ? 1.f : 0.f;
        sq += valid ? ss * inv * inv : 0.f;
      }
    };

// counted vmcnt: steady state keeps 10-12 loads in flight; drains 8,6,4,2,0
#define PSTEP(T, NW, SA, SB)                          \
    asm volatile("s_waitcnt vmcnt(" #NW ")");         \
    __builtin_amdgcn_sched_barrier(0);                \
    consume(SA, SB, T);

    PSTEP(0, 10, s0a, s0b)  gload8(s0a, s0b, emb + (size_t)rI[6] * D + lp * 8);
    PSTEP(1, 10, s1a, s1b)  gload8(s1a, s1b, emb + (size_t)rI[7] * D + lp * 8);
    PSTEP(2, 10, s2a, s2b)  gload8(s2a, s2b, emb + (size_t)rI[8] * D + lp * 8);
    PSTEP(3, 10, s3a, s3b)
    PSTEP(4, 8,  s4a, s4b)
    PSTEP(5, 6,  s5a, s5b)
    PSTEP(6, 4,  s0a, s0b)
    PSTEP(7, 2,  s1a, s1b)
    PSTEP(8, 0,  s2a, s2b)
#undef PSTEP

    // cross-group reduce (groups share the lp->dim map)
#pragma unroll
    for (int off = 16; off <= 32; off <<= 1) {
      accA.x += __shfl_xor(accA.x, off);  accA.y += __shfl_xor(accA.y, off);
      accA.z += __shfl_xor(accA.z, off);  accA.w += __shfl_xor(accA.w, off);
      accB.x += __shfl_xor(accB.x, off);  accB.y += __shfl_xor(accB.y, off);
      accB.z += __shfl_xor(accB.z, off);  accB.w += __shfl_xor(accB.w, off);
      cnt += __shfl_xor(cnt, off);
      sq += __shfl_xor(sq, off);
    }

    if (lane < 16) {
      *(float4*)&sR[wave][lp * 8] = accA;
      *(float4*)&sR[wave][lp * 8 + 4] = accB;
    }
    if (lane == 0) { sR[wave][128] = cnt; sR[wave][129] = sq; }
    __syncthreads();
    if (tid < 130) {
      float s = 0.f;
#pragma unroll
      for (int w = 0; w < 8; ++w) s += sR[w][tid];
      oct[(size_t)b * OCTW + tid] = s;
    }
  };

  // parity stagger: half the chip streams logits while half gathers emb
  if (b & 1) { ce_phase(); __syncthreads(); proto_phase(); }
  else       { proto_phase(); __syncthreads(); ce_phase(); }
}

// ---------------- K3: per-class stats ---------------------------------------
__global__ __launch_bounds__(128) void class_kernel(
    const float* __restrict__ oct, float* __restrict__ res) {
  __shared__ float sM[2];
  const int c = blockIdx.x, t = threadIdx.x;
  float s = 0.f, n = 0.f, sq = 0.f;
#pragma unroll
  for (int o = 0; o < 16; ++o) {
    const float* f = oct + (size_t)(c * 16 + o) * OCTW;
    s += f[t];
    n += f[128];
    sq += f[129];
  }
  const float safe = fmaxf(n, 1.f);
  const float mu = s / safe;
  float msq = mu * mu;
#pragma unroll
  for (int off = 1; off < 64; off <<= 1) msq += __shfl_xor(msq, off);
  if ((t & 63) == 0) sM[t >> 6] = msq;
  __syncthreads();
  if (t == 0) {
    const float ssd = sq - n * (sM[0] + sM[1]);
    const bool valid = n > 1.f;
    res[c] = valid ? ssd / safe : 0.f;
    res[C + c] = valid ? 1.f : 0.f;
  }
}

// ---------------- K4: final scalar ------------------------------------------
__global__ __launch_bounds__(256) void final_kernel(
    const float* __restrict__ ceB, const float* __restrict__ res,
    float* __restrict__ out) {
  __shared__ float sv[4][3];
  const int tid = threadIdx.x, wave = tid >> 6, lane = tid & 63;
  float ce = 0.f;
  for (int i = tid; i < FB; i += 256) ce += ceB[i];
  float pr = 0.f, nv = 0.f;
  if (wave == 0) { pr = res[lane]; nv = res[C + lane]; }
#pragma unroll
  for (int off = 1; off < 64; off <<= 1) {
    ce += __shfl_xor(ce, off);
    pr += __shfl_xor(pr, off);
    nv += __shfl_xor(nv, off);
  }
  if (lane == 0) { sv[wave][0] = ce; sv[wave][1] = pr; sv[wave][2] = nv; }
  __syncthreads();
  if (tid == 0) {
    const float c2 = sv[0][0] + sv[1][0] + sv[2][0] + sv[3][0];
    const float p2 = sv[0][1] + sv[1][1] + sv[2][1] + sv[3][1];
    const float n2 = sv[0][2] + sv[1][2] + sv[2][2] + sv[3][2];
    out[0] = 0.5f * (c2 / (float)N_ROWS) + 0.5f * (p2 / fmaxf(n2, 1.f));
  }
}

extern "C" void kernel_launch(void* const* d_in, const int* in_sizes, int n_in,
                              void* d_out, int out_size, void* d_ws, size_t ws_size,
                              hipStream_t stream) {
  const float* emb = (const float*)d_in[0];
  const float* logits = (const float*)d_in[1];
  const int* labels = (const int*)d_in[2];
  int* wsi = (int*)d_ws;
  float* wsf = (float*)d_ws;
  float* out = (float*)d_out;

  int* idx = wsi + OFF_IDX;
  int* cnts = wsi + OFF_CNT;
  float* ceB = wsf + OFF_CEB;
  float* oct = wsf + OFF_OCT;
  float* res = wsf + OFF_RES;

  hipMemsetAsync(cnts, 0, C * sizeof(int), stream);
  build_kernel<<<BB, 1024, 0, stream>>>(labels, idx, cnts);
  fused_kernel<<<FB, FT, 0, stream>>>(emb, logits, labels, idx, cnts, ceB, oct);
  class_kernel<<<C, 128, 0, stream>>>(oct, res);
  final_kernel<<<1, 256, 0, stream>>>(ceB, res, out);
}

// Round 13
// 51.994 us; speedup vs baseline: 1.2394x; 1.0187x over previous
//
#include <hip/hip_runtime.h>
#include <math.h>

#define N_ROWS 262144
#define D 128
#define C 64
#define CSTRIDE 4608      // padded per-class index slot (count ~4096 + 8 sigma)
#define BB 64             // build blocks; 4096 rows each
#define FB 2048           // fused blocks = 64 classes x 32 octants; 128 CE rows each
#define FT 512
#define TMAX 5            // ceil(CSTRIDE / (1024 groups per class))
#define OCTW 132          // per-block partial: 128 sums + cnt + sq + pad

// ws layout (4-byte units)
#define OFF_IDX    0                          // int[C*CSTRIDE]
#define OFF_CNT    (C * CSTRIDE)              // int[C]
#define OFF_CEB    (OFF_CNT + C)              // float[FB]
#define OFF_OCT    (OFF_CEB + FB)             // float[FB*OCTW]
#define OFF_RES    (OFF_OCT + FB * OCTW)      // float[2*C]

// asm-issued 32B gather: compiler cannot sink/serialize these
__device__ __forceinline__ void gload8(float4& a, float4& b, const float* p) {
  asm volatile("global_load_dwordx4 %0, %2, off\n\t"
               "global_load_dwordx4 %1, %2, off offset:16"
               : "=&v"(a), "=&v"(b)
               : "v"(p));
}

// ---------------- K1: one-shot index build (hist+scan+scatter fused) --------
__global__ __launch_bounds__(1024) void build_kernel(
    const int* __restrict__ labels, int* __restrict__ idx,
    int* __restrict__ cnts) {
  __shared__ int sH[C];
  __shared__ int sBase[C];
  const int t = threadIdx.x, b = blockIdx.x;
  if (t < C) sH[t] = 0;
  __syncthreads();
  const int row = b * 4096 + t * 4;
  const int4 l = *(const int4*)(labels + row);
  const int p0 = atomicAdd(&sH[l.x], 1);
  const int p1 = atomicAdd(&sH[l.y], 1);
  const int p2 = atomicAdd(&sH[l.z], 1);
  const int p3 = atomicAdd(&sH[l.w], 1);
  __syncthreads();
  if (t < C) sBase[t] = atomicAdd(&cnts[t], sH[t]);
  __syncthreads();
  idx[l.x * CSTRIDE + sBase[l.x] + p0] = row;
  idx[l.y * CSTRIDE + sBase[l.y] + p1] = row + 1;
  idx[l.z * CSTRIDE + sBase[l.z] + p2] = row + 2;
  idx[l.w * CSTRIDE + sBase[l.w] + p3] = row + 3;
}

// ---------------- K2: fused CE + class-gather, parity-staggered -------------
__global__ __launch_bounds__(FT, 4) void fused_kernel(
    const float* __restrict__ emb, const float* __restrict__ logits,
    const int* __restrict__ labels, const int* __restrict__ idxArr,
    const int* __restrict__ cnts, float* __restrict__ ceB,
    float* __restrict__ oct) {
  __shared__ float sCe[8];
  __shared__ float sR[8][OCTW];

  const int tid = threadIdx.x;
  const int wave = tid >> 6, lane = tid & 63;
  const int g = lane >> 4, lp = lane & 15;
  const int b = blockIdx.x;

  // ---- CE phase: 128 sequential rows, proven streaming skeleton ----
  auto ce_phase = [&]() {
    const int rowBase = b * 128 + wave * 16 + g;
    float ce_acc = 0.f;
    float4 tA, tB;
    int labA = 0, labB = 0;
    tA = *(const float4*)(logits + (size_t)rowBase * C + lp * 4);
    labA = labels[rowBase];
    tB = tA;
#pragma unroll
    for (int it = 0; it < 4; ++it) {
      const float4 t4 = (it & 1) ? tB : tA;
      const int lab = (it & 1) ? labB : labA;
      if (it + 1 < 4) {
        const int row = rowBase + (it + 1) * 4;
        if (it & 1) {
          tA = *(const float4*)(logits + (size_t)row * C + lp * 4);
          labA = labels[row];
        } else {
          tB = *(const float4*)(logits + (size_t)row * C + lp * 4);
          labB = labels[row];
        }
      }
      float p = __expf(t4.x) + __expf(t4.y) + __expf(t4.z) + __expf(t4.w);
      float tl = 0.f;
      if ((lab >> 2) == lp) {
        const int k = lab & 3;
        tl = k == 0 ? t4.x : k == 1 ? t4.y : k == 2 ? t4.z : t4.w;
      }
      p += __shfl_xor(p, 1);  tl += __shfl_xor(tl, 1);
      p += __shfl_xor(p, 2);  tl += __shfl_xor(tl, 2);
      p += __shfl_xor(p, 4);  tl += __shfl_xor(tl, 4);
      p += __shfl_xor(p, 8);  tl += __shfl_xor(tl, 8);
      if (lp == 0) ce_acc += __logf(p) - tl;
    }
    ce_acc += __shfl_xor(ce_acc, 16);
    ce_acc += __shfl_xor(ce_acc, 32);
    if (lane == 0) sCe[wave] = ce_acc;
    __syncthreads();
    if (tid == 0) {
      float s = 0.f;
#pragma unroll
      for (int w = 0; w < 8; ++w) s += sCe[w];
      ceB[b] = s;
    }
  };

  // ---- proto phase: asm-forced depth-5 gather pipeline (depth == TMAX) ----
  auto proto_phase = [&]() {
    const int c = b >> 5, o = b & 31;
    const int gg = o * 32 + wave * 4 + g;    // group slot in class: 0..1023
    const int n = cnts[c];
    const int nm1 = (n > 0) ? n - 1 : 0;
    const int* ip = idxArr + c * CSTRIDE;

    int rI[TMAX];
#pragma unroll
    for (int t = 0; t < TMAX; ++t) {
      const int e = gg + 1024 * t;
      rI[t] = ip[e < nm1 ? e : nm1];
    }
    // force index loads complete BEFORE the pipeline, so the compiler never
    // inserts a draining vmcnt(0) between our asm loads
#pragma unroll
    for (int t = 0; t < TMAX; ++t) asm volatile("" :: "v"(rI[t]));
    __builtin_amdgcn_sched_barrier(0);

    float4 s0a, s0b, s1a, s1b, s2a, s2b, s3a, s3b, s4a, s4b;
    gload8(s0a, s0b, emb + (size_t)rI[0] * D + lp * 8);
    gload8(s1a, s1b, emb + (size_t)rI[1] * D + lp * 8);
    gload8(s2a, s2b, emb + (size_t)rI[2] * D + lp * 8);
    gload8(s3a, s3b, emb + (size_t)rI[3] * D + lp * 8);
    gload8(s4a, s4b, emb + (size_t)rI[4] * D + lp * 8);

    float4 accA = {0.f, 0.f, 0.f, 0.f}, accB = {0.f, 0.f, 0.f, 0.f};
    float cnt = 0.f, sq = 0.f;

    auto consume = [&](const float4 ea, const float4 eb, const int t) {
      float ss = ea.x * ea.x + ea.y * ea.y + ea.z * ea.z + ea.w * ea.w +
                 eb.x * eb.x + eb.y * eb.y + eb.z * eb.z + eb.w * eb.w;
      ss += __shfl_xor(ss, 1);
      ss += __shfl_xor(ss, 2);
      ss += __shfl_xor(ss, 4);
      ss += __shfl_xor(ss, 8);
      const float inv = 1.0f / fmaxf(sqrtf(ss), 1e-12f);
      const bool valid = (gg + 1024 * t) < n;
      const float sc = valid ? inv : 0.f;    // validity folded into the scale
      accA.x += ea.x * sc;  accA.y += ea.y * sc;
      accA.z += ea.z * sc;  accA.w += ea.w * sc;
      accB.x += eb.x * sc;  accB.y += eb.y * sc;
      accB.z += eb.z * sc;  accB.w += eb.w * sc;
      if (lp == 0) {
        cnt += valid ? 1.f : 0.f;
        sq += valid ? ss * inv * inv : 0.f;
      }
    };

// counted vmcnt drain: 8,6,4,2,0 (10 loads in flight at start)
#define PSTEP(T, NW, SA, SB)                          \
    asm volatile("s_waitcnt vmcnt(" #NW ")");         \
    __builtin_amdgcn_sched_barrier(0);                \
    consume(SA, SB, T);

    PSTEP(0, 8, s0a, s0b)
    PSTEP(1, 6, s1a, s1b)
    PSTEP(2, 4, s2a, s2b)
    PSTEP(3, 2, s3a, s3b)
    PSTEP(4, 0, s4a, s4b)
#undef PSTEP

    // cross-group reduce (groups share the lp->dim map)
#pragma unroll
    for (int off = 16; off <= 32; off <<= 1) {
      accA.x += __shfl_xor(accA.x, off);  accA.y += __shfl_xor(accA.y, off);
      accA.z += __shfl_xor(accA.z, off);  accA.w += __shfl_xor(accA.w, off);
      accB.x += __shfl_xor(accB.x, off);  accB.y += __shfl_xor(accB.y, off);
      accB.z += __shfl_xor(accB.z, off);  accB.w += __shfl_xor(accB.w, off);
      cnt += __shfl_xor(cnt, off);
      sq += __shfl_xor(sq, off);
    }

    if (lane < 16) {
      *(float4*)&sR[wave][lp * 8] = accA;
      *(float4*)&sR[wave][lp * 8 + 4] = accB;
    }
    if (lane == 0) { sR[wave][128] = cnt; sR[wave][129] = sq; }
    __syncthreads();
    if (tid < 130) {
      float s = 0.f;
#pragma unroll
      for (int w = 0; w < 8; ++w) s += sR[w][tid];
      oct[(size_t)b * OCTW + tid] = s;
    }
  };

  // parity stagger: half the chip streams logits while half gathers emb
  if (b & 1) { ce_phase(); __syncthreads(); proto_phase(); }
  else       { proto_phase(); __syncthreads(); ce_phase(); }
}

// ---------------- K3: per-class stats ---------------------------------------
__global__ __launch_bounds__(128) void class_kernel(
    const float* __restrict__ oct, float* __restrict__ res) {
  __shared__ float sM[2];
  const int c = blockIdx.x, t = threadIdx.x;
  float s = 0.f, n = 0.f, sq = 0.f;
#pragma unroll
  for (int o = 0; o < 32; ++o) {
    const float* f = oct + (size_t)(c * 32 + o) * OCTW;
    s += f[t];
    n += f[128];
    sq += f[129];
  }
  const float safe = fmaxf(n, 1.f);
  const float mu = s / safe;
  float msq = mu * mu;
#pragma unroll
  for (int off = 1; off < 64; off <<= 1) msq += __shfl_xor(msq, off);
  if ((t & 63) == 0) sM[t >> 6] = msq;
  __syncthreads();
  if (t == 0) {
    const float ssd = sq - n * (sM[0] + sM[1]);
    const bool valid = n > 1.f;
    res[c] = valid ? ssd / safe : 0.f;
    res[C + c] = valid ? 1.f : 0.f;
  }
}

// ---------------- K4: final scalar ------------------------------------------
__global__ __launch_bounds__(256) void final_kernel(
    const float* __restrict__ ceB, const float* __restrict__ res,
    float* __restrict__ out) {
  __shared__ float sv[4][3];
  const int tid = threadIdx.x, wave = tid >> 6, lane = tid & 63;
  float ce = 0.f;
  for (int i = tid; i < FB; i += 256) ce += ceB[i];
  float pr = 0.f, nv = 0.f;
  if (wave == 0) { pr = res[lane]; nv = res[C + lane]; }
#pragma unroll
  for (int off = 1; off < 64; off <<= 1) {
    ce += __shfl_xor(ce, off);
    pr += __shfl_xor(pr, off);
    nv += __shfl_xor(nv, off);
  }
  if (lane == 0) { sv[wave][0] = ce; sv[wave][1] = pr; sv[wave][2] = nv; }
  __syncthreads();
  if (tid == 0) {
    const float c2 = sv[0][0] + sv[1][0] + sv[2][0] + sv[3][0];
    const float p2 = sv[0][1] + sv[1][1] + sv[2][1] + sv[3][1];
    const float n2 = sv[0][2] + sv[1][2] + sv[2][2] + sv[3][2];
    out[0] = 0.5f * (c2 / (float)N_ROWS) + 0.5f * (p2 / fmaxf(n2, 1.f));
  }
}

extern "C" void kernel_launch(void* const* d_in, const int* in_sizes, int n_in,
                              void* d_out, int out_size, void* d_ws, size_t ws_size,
                              hipStream_t stream) {
  const float* emb = (const float*)d_in[0];
  const float* logits = (const float*)d_in[1];
  const int* labels = (const int*)d_in[2];
  int* wsi = (int*)d_ws;
  float* wsf = (float*)d_ws;
  float* out = (float*)d_out;

  int* idx = wsi + OFF_IDX;
  int* cnts = wsi + OFF_CNT;
  float* ceB = wsf + OFF_CEB;
  float* oct = wsf + OFF_OCT;
  float* res = wsf + OFF_RES;

  hipMemsetAsync(cnts, 0, C * sizeof(int), stream);
  build_kernel<<<BB, 1024, 0, stream>>>(labels, idx, cnts);
  fused_kernel<<<FB, FT, 0, stream>>>(emb, logits, labels, idx, cnts, ceB, oct);
  class_kernel<<<C, 128, 0, stream>>>(oct, res);
  final_kernel<<<1, 256, 0, stream>>>(ceB, res, out);
}